// Round 1
// baseline (153.222 us; speedup 1.0000x reference)
//
#include <hip/hip_runtime.h>

#define N_WORDS   16384
#define L_CHARS   16
#define CHAR_SIZE 128
#define C_EMB     64
#define CONV_L    256
#define KERNEL_K  3
#define VOCAB     50000
#define D_EMB     300
#define OUT_STRIDE (CONV_L + D_EMB)   // 556

static __device__ __forceinline__ float4 f4add(float4 a, float4 b) {
    return make_float4(a.x + b.x, a.y + b.y, a.z + b.z, a.w + b.w);
}
static __device__ __forceinline__ float4 f4max(float4 a, float4 b) {
    return make_float4(fmaxf(a.x, b.x), fmaxf(a.y, b.y),
                       fmaxf(a.z, b.z), fmaxf(a.w, b.w));
}

// Kernel 1: fold char-embedding into conv weights.
// T[((c*3)+k)*256 + o] = sum_i emb[c][i] * w[o][i][k]
// 128*3*256 = 98304 entries, 64 MACs each — trivial (~µs).
__global__ void build_table(const float* __restrict__ emb,
                            const float* __restrict__ w,
                            float* __restrict__ T) {
    int idx = blockIdx.x * blockDim.x + threadIdx.x;
    if (idx >= CHAR_SIZE * KERNEL_K * CONV_L) return;
    int o  = idx & (CONV_L - 1);
    int ck = idx >> 8;            // c*3 + k
    int k  = ck % 3;
    int c  = ck / 3;
    const float* erow = emb + c * C_EMB;
    const float* wrow = w + o * (C_EMB * KERNEL_K) + k;
    float s = 0.f;
    #pragma unroll
    for (int i = 0; i < C_EMB; ++i)
        s += erow[i] * wrow[i * KERNEL_K];
    T[idx] = s;
}

// Kernel 2 (fused): blocks [0, char_blocks) do the conv/maxpool path,
// blocks [char_blocks, char_blocks+word_blocks) do the word-emb gather.
// Char path: one wave per word; lane handles 4 consecutive channels
// (64 lanes * 4 = 256 channels). Sliding 3-deep accumulator over the 18
// output positions: after char j, y[j] is complete.
__global__ __launch_bounds__(256)
void main_kernel(const int* __restrict__ X,
                 const int* __restrict__ Xw,
                 const float* __restrict__ T,
                 const float* __restrict__ conv_b,
                 const float* __restrict__ word_emb,
                 float* __restrict__ out,
                 int char_blocks, int word_blocks) {
    const int lane = threadIdx.x & 63;
    const int waveInBlock = threadIdx.x >> 6;

    if ((int)blockIdx.x < char_blocks) {
        const int wavesTotal = char_blocks * 4;
        const int waveId = blockIdx.x * 4 + waveInBlock;
        // per-lane bias for its 4 channels (hoisted out of the word loop)
        const float4 b4 = *(const float4*)(conv_b + lane * 4);
        const float4 zero = make_float4(0.f, 0.f, 0.f, 0.f);

        for (int n = waveId; n < N_WORDS; n += wavesTotal) {
            // all lanes broadcast-load the word's 16 chars (64 B, one cache line)
            const int4* xr = (const int4*)(X + n * L_CHARS);
            int4 q0 = xr[0], q1 = xr[1], q2 = xr[2], q3 = xr[3];
            int cs[16] = {q0.x, q0.y, q0.z, q0.w,
                          q1.x, q1.y, q1.z, q1.w,
                          q2.x, q2.y, q2.z, q2.w,
                          q3.x, q3.y, q3.z, q3.w};

            float4 a0 = zero;                     // partial of y[j]   entering iter j
            float4 a1 = zero;                     // partial of y[j+1] entering iter j
            float4 m  = make_float4(-1e30f, -1e30f, -1e30f, -1e30f);

            #pragma unroll
            for (int j = 0; j < L_CHARS; ++j) {
                const float4* Tc =
                    (const float4*)(T + cs[j] * (KERNEL_K * CONV_L)) + lane;
                float4 t0 = Tc[0];     // k=0 row (floats [0,256))
                float4 t1 = Tc[64];    // k=1 row
                float4 t2 = Tc[128];   // k=2 row
                float4 yj = f4add(a0, t2);   // y[j] complete
                m  = f4max(m, yj);
                a0 = f4add(a1, t1);          // partial y[j+1]
                a1 = t0;                     // partial y[j+2]
            }
            // tail positions: y[16] = a0, y[17] = a1
            m = f4max(m, a0);
            m = f4max(m, a1);
            // max_t relu(y+b) = max(0, b + max_t y) since b is constant over t
            float4 r = f4max(f4add(m, b4), zero);
            *(float4*)(out + (size_t)n * OUT_STRIDE + lane * 4) = r;
        }
    } else {
        // word-embedding gather: one wave per word pass, 75 float4 per row
        const int wbIdx = (int)blockIdx.x - char_blocks;
        const int wavesTotal = word_blocks * 4;
        const int waveId = wbIdx * 4 + waveInBlock;
        for (int n = waveId; n < N_WORDS; n += wavesTotal) {
            int widx = Xw[n];
            const float4* src = (const float4*)(word_emb + (size_t)widx * D_EMB);
            float4* dst = (float4*)(out + (size_t)n * OUT_STRIDE + CONV_L);
            float4 v = src[lane];            // lanes 0..63 -> float4 0..63
            dst[lane] = v;
            if (lane < (D_EMB / 4 - 64)) {   // remaining 11 float4
                dst[64 + lane] = src[64 + lane];
            }
        }
    }
}

extern "C" void kernel_launch(void* const* d_in, const int* in_sizes, int n_in,
                              void* d_out, int out_size, void* d_ws, size_t ws_size,
                              hipStream_t stream) {
    const int*   X    = (const int*)d_in[0];
    const int*   Xw   = (const int*)d_in[1];
    const float* emb  = (const float*)d_in[2];
    const float* w    = (const float*)d_in[3];
    const float* b    = (const float*)d_in[4];
    const float* we   = (const float*)d_in[5];
    float* out = (float*)d_out;
    float* T   = (float*)d_ws;   // needs 128*3*256*4 = 393216 B of workspace

    build_table<<<(CHAR_SIZE * KERNEL_K * CONV_L + 255) / 256, 256, 0, stream>>>(
        emb, w, T);

    const int CB = 1024;  // char-path blocks: 4096 waves, 4 words/wave
    const int WB = 256;   // word-path blocks: 1024 waves, 16 words/wave
    main_kernel<<<CB + WB, 256, 0, stream>>>(X, Xw, T, b, we, out, CB, WB);
}

// Round 2
// 135.924 us; speedup vs baseline: 1.1273x; 1.1273x over previous
//
#include <hip/hip_runtime.h>

#define N_WORDS   16384
#define L_CHARS   16
#define CHAR_SIZE 128
#define C_EMB     64
#define CONV_L    256
#define KERNEL_K  3
#define VOCAB     50000
#define D_EMB     300
#define OUT_STRIDE (CONV_L + D_EMB)   // 556

typedef _Float16 half8 __attribute__((ext_vector_type(8)));

// ---------------------------------------------------------------------------
// Kernel A: transpose conv_w (O,I,K) -> Wt (I,K,O) so the build kernel reads
// coalesced. Reads coalesced (linear over w), writes scattered (fine).
// 49152 elements.
__global__ void transpose_w(const float* __restrict__ w, float* __restrict__ Wt) {
    int tid = blockIdx.x * blockDim.x + threadIdx.x;
    if (tid >= CONV_L * C_EMB * KERNEL_K) return;
    int o = tid / (C_EMB * KERNEL_K);
    int r = tid - o * (C_EMB * KERNEL_K);
    int i = r / KERNEL_K;
    int k = r - i * KERNEL_K;
    Wt[i * (KERNEL_K * CONV_L) + k * CONV_L + o] = w[tid];
}

// ---------------------------------------------------------------------------
// Kernel B: T_h[c][k][o] = (half) sum_i emb[c][i] * Wt[i][k][o]
// grid 384 x 256: block b covers c = b/3, ko = (b%3)*256 + tid.
// emb access is wave-uniform (s_load); Wt access coalesced (1 KB/wave-instr).
__global__ void build_table(const float* __restrict__ emb,
                            const float* __restrict__ Wt,
                            _Float16* __restrict__ Th) {
    int c  = blockIdx.x / 3;
    int ko = (blockIdx.x % 3) * 256 + threadIdx.x;
    const float* erow = emb + c * C_EMB;
    float s = 0.f;
    #pragma unroll
    for (int i = 0; i < C_EMB; ++i)
        s += erow[i] * Wt[i * (KERNEL_K * CONV_L) + ko];
    Th[c * (KERNEL_K * CONV_L) + ko] = (_Float16)s;
}

// ---------------------------------------------------------------------------
// Kernel C (fused main): blocks [0, WB) gather word embeddings; blocks
// [WB, WB+CB) do the char conv/maxpool path.
// Char path: each wave processes a PAIR of words — lanes 0-31 word 2p,
// lanes 32-63 word 2p+1. Each lane owns 8 consecutive channels (32 lanes x 8
// = 256). T rows are fp16: one half8 (16 B) load per (char, k) per lane, so
// every wave-load is a dense 1 KB transaction and L2 bytes are halved vs fp32.
__global__ __launch_bounds__(256, 4)
void main_kernel(const int* __restrict__ X,
                 const int* __restrict__ Xw,
                 const _Float16* __restrict__ Th,
                 const float* __restrict__ conv_b,
                 const float* __restrict__ word_emb,
                 float* __restrict__ out,
                 int word_blocks, int char_blocks) {
    const int lane = threadIdx.x & 63;
    const int waveInBlock = threadIdx.x >> 6;

    if ((int)blockIdx.x < word_blocks) {
        // ---- word-embedding gather: 75 float4 per row ----
        const int wavesTotal = word_blocks * 4;
        const int waveId = blockIdx.x * 4 + waveInBlock;
        for (int n = waveId; n < N_WORDS; n += wavesTotal) {
            int widx = Xw[n];
            const float4* src = (const float4*)(word_emb + (size_t)widx * D_EMB);
            float4* dst = (float4*)(out + (size_t)n * OUT_STRIDE + CONV_L);
            dst[lane] = src[lane];
            if (lane < (D_EMB / 4 - 64)) {
                dst[64 + lane] = src[64 + lane];
            }
        }
    } else {
        // ---- char conv + maxpool ----
        const int wavesTotal = char_blocks * 4;
        const int waveId = ((int)blockIdx.x - word_blocks) * 4 + waveInBlock;
        const int sel = lane >> 5;   // which word of the pair
        const int l32 = lane & 31;   // lane within half-wave; owns channels [l32*8, l32*8+8)

        float bias[8];
        {
            float4 b0 = ((const float4*)(conv_b + l32 * 8))[0];
            float4 b1 = ((const float4*)(conv_b + l32 * 8))[1];
            bias[0]=b0.x; bias[1]=b0.y; bias[2]=b0.z; bias[3]=b0.w;
            bias[4]=b1.x; bias[5]=b1.y; bias[6]=b1.z; bias[7]=b1.w;
        }

        for (int p = waveId; p < N_WORDS / 2; p += wavesTotal) {
            const int n = p * 2 + sel;
            const int4* xr = (const int4*)(X + n * L_CHARS);
            int4 q0 = xr[0], q1 = xr[1], q2 = xr[2], q3 = xr[3];
            int cs[16] = {q0.x, q0.y, q0.z, q0.w,
                          q1.x, q1.y, q1.z, q1.w,
                          q2.x, q2.y, q2.z, q2.w,
                          q3.x, q3.y, q3.z, q3.w};

            float a0[8], a1[8], m[8];
            #pragma unroll
            for (int e = 0; e < 8; ++e) { a0[e] = 0.f; a1[e] = 0.f; m[e] = -1e30f; }

            #pragma unroll
            for (int j = 0; j < L_CHARS; ++j) {
                const half8* Tc = (const half8*)(Th + cs[j] * (KERNEL_K * CONV_L));
                half8 t0 = Tc[l32];        // k=0 row
                half8 t1 = Tc[32 + l32];   // k=1 row
                half8 t2 = Tc[64 + l32];   // k=2 row
                #pragma unroll
                for (int e = 0; e < 8; ++e) {
                    float yj = a0[e] + (float)t2[e];   // y[j] complete
                    m[e]  = fmaxf(m[e], yj);
                    a0[e] = a1[e] + (float)t1[e];      // partial y[j+1]
                    a1[e] = (float)t0[e];              // partial y[j+2]
                }
            }
            // tails: y[16] = a0, y[17] = a1; fold bias+relu outside the max
            float4 r0, r1;
            float r[8];
            #pragma unroll
            for (int e = 0; e < 8; ++e) {
                float mm = fmaxf(fmaxf(m[e], a0[e]), a1[e]);
                r[e] = fmaxf(mm + bias[e], 0.f);
            }
            r0 = make_float4(r[0], r[1], r[2], r[3]);
            r1 = make_float4(r[4], r[5], r[6], r[7]);
            float4* dst = (float4*)(out + (size_t)n * OUT_STRIDE + l32 * 8);
            dst[0] = r0;
            dst[1] = r1;
        }
    }
}

extern "C" void kernel_launch(void* const* d_in, const int* in_sizes, int n_in,
                              void* d_out, int out_size, void* d_ws, size_t ws_size,
                              hipStream_t stream) {
    const int*   X    = (const int*)d_in[0];
    const int*   Xw   = (const int*)d_in[1];
    const float* emb  = (const float*)d_in[2];
    const float* w    = (const float*)d_in[3];
    const float* b    = (const float*)d_in[4];
    const float* we   = (const float*)d_in[5];
    float* out = (float*)d_out;

    // ws layout: Th (fp16 table, 128*768*2 = 196608 B) | Wt (fp32, 196608 B)
    _Float16* Th = (_Float16*)d_ws;
    float*    Wt = (float*)((char*)d_ws + CHAR_SIZE * KERNEL_K * CONV_L * sizeof(_Float16));

    transpose_w<<<(CONV_L * C_EMB * KERNEL_K + 255) / 256, 256, 0, stream>>>(w, Wt);
    build_table<<<CHAR_SIZE * KERNEL_K, 256, 0, stream>>>(emb, Wt, Th);

    const int WB = 256;   // word-gather blocks: 1024 waves, 16 words each
    const int CB = 1024;  // char-path blocks: 4096 waves, 2 word-pairs each
    main_kernel<<<WB + CB, 256, 0, stream>>>(X, Xw, Th, b, we, out, WB, CB);
}